// Round 19
// baseline (167.226 us; speedup 1.0000x reference)
//
#include <hip/hip_runtime.h>
#include <hip/hip_bf16.h>

typedef __attribute__((ext_vector_type(8))) short     bf16x8;
typedef __attribute__((ext_vector_type(4))) float     f32x4;
typedef __attribute__((ext_vector_type(4))) unsigned  u32x4;

// ---------------------------------------------------------------------------
// helpers
// ---------------------------------------------------------------------------
__device__ inline unsigned short bf16_rn(float x) {
  unsigned u = __float_as_uint(x);
  unsigned r = (u + 0x7FFFu + ((u >> 16) & 1u)) >> 16;
  return (unsigned short)r;
}
// compiler-scheduled packed bf16 convert (m240: inline-asm cvt_pk blocks
// scheduling; intrinsic emits the same v_cvt_pk_bf16_f32, RNE rounding ->
// bit-identical). memcpy instead of bit_cast: __hip_bfloat162 is not
// trivially copyable.
__device__ inline unsigned cvt_pk_bf16(float a, float b) {
  __hip_bfloat162 h = __float22bfloat162_rn(float2{a, b});
  unsigned r;
  __builtin_memcpy(&r, &h, 4);
  return r;
}
__device__ inline void pin4f(f32x4& v) { asm("" : "+v"(v)); }
__device__ inline void pin4u(u32x4& v) { asm("" : "+v"(v)); }
// compile-time-only ordering pin (per-wave LDS is in-order in HW; R7/R17)
__device__ inline void cbar() { asm volatile("" ::: "memory"); }
__device__ inline float tanh_fast(float v) {
  float vv = fminf(fmaxf(v, -15.f), 15.f);
  float e = __expf(2.f * vv);
  return (e - 1.f) * __builtin_amdgcn_rcpf(e + 1.f);
}

// ---------------------------------------------------------------------------
// Merged prologue: blocks 0..31 eig | 32..47 argmax | 48..58 wpack
// ---------------------------------------------------------------------------
__global__ __launch_bounds__(256) void prologue_kernel(
    const float* __restrict__ Kt, const float* __restrict__ comm,
    const float* __restrict__ W0, const float* __restrict__ W1,
    const float* __restrict__ W2,
    float* __restrict__ Gout, int* __restrict__ cls,
    unsigned* __restrict__ wfrag)
{
  const int b = blockIdx.x;
  const int t = threadIdx.x;

  if (b < 32) {
    __shared__ double Kd[64];
    __shared__ double Pw[2][64];
    __shared__ double psum[8];
    __shared__ double coefs[9];
    __shared__ double rts[16];
    __shared__ double Gpart[64][8];

    const int tl = t & 63;
    const int row = tl >> 3, col = tl & 7;

    if (t < 64) Kd[tl] = (double)Kt[b * 64 + tl];
    __syncthreads();
    if (t < 64) Pw[0][tl] = Kd[tl];
    __syncthreads();

    int cur = 0;
    for (int p = 1; p <= 8; ++p) {
      if (t == 0) {
        double tr = 0.0;
        for (int d = 0; d < 8; ++d) tr += Pw[cur][d * 9];
        psum[p - 1] = tr;
      }
      if (p < 8 && t < 64) {
        double sacc = 0.0;
        for (int k = 0; k < 8; ++k) sacc += Pw[cur][row * 8 + k] * Kd[k * 8 + col];
        Pw[cur ^ 1][tl] = sacc;
      }
      __syncthreads();
      cur ^= 1;
    }

    if (t == 0) {
      double a[9];
      a[0] = 1.0;
      for (int k = 1; k <= 8; ++k) {
        double ssum = psum[k - 1];
        for (int i = 1; i < k; ++i) ssum += a[i] * psum[k - i - 1];
        a[k] = -ssum / (double)k;
      }
      for (int k = 0; k <= 8; ++k) coefs[k] = a[k];
    }
    __syncthreads();

    if (t < 8) {
      double a8[9];
      #pragma unroll
      for (int k = 0; k <= 8; ++k) a8[k] = coefs[k];
      double zre = 1.0, zim = 0.0;
      for (int q = 0; q <= t; ++q) {
        double t1 = zre * 0.4 - zim * 0.9;
        double t2 = zre * 0.9 + zim * 0.4;
        zre = t1; zim = t2;
      }
      for (int it = 0; it < 20; ++it) {
        double pre = a8[0], pim = 0.0;
        #pragma unroll
        for (int k = 1; k <= 8; ++k) {
          double t1 = pre * zre - pim * zim + a8[k];
          double t2 = pre * zim + pim * zre;
          pre = t1; pim = t2;
        }
        double dre = 1.0, dim = 0.0;
        for (int j = 0; j < 8; ++j) {
          double ore = __shfl(zre, j, 64);
          double oim = __shfl(zim, j, 64);
          if (j != t) {
            double sre = zre - ore, sim = zim - oim;
            double t1 = dre * sre - dim * sim;
            double t2 = dre * sim + dim * sre;
            dre = t1; dim = t2;
          }
        }
        double d2 = dre * dre + dim * dim;
        if (d2 < 1e-60) d2 = 1e-60;
        double qre = (pre * dre + pim * dim) / d2;
        double qim = (pim * dre - pre * dim) / d2;
        zre -= qre; zim -= qim;
      }
      rts[t] = zre; rts[8 + t] = zim;
    }
    __syncthreads();

    if (t < 64) {
      double lre[8], lim[8];
      #pragma unroll
      for (int j = 0; j < 8; ++j) { lre[j] = rts[j]; lim[j] = rts[8 + j]; }

      bool keep[8]; bool any = false;
      #pragma unroll
      for (int j = 0; j < 8; ++j) {
        double sre = lre[j] + 1e-10, sim = lim[j] + 1e-10;
        double amod = sqrt(sre * sre + sim * sim);
        keep[j] = (amod <= 1.1) && (amod >= 0.9);
        any = any || keep[j];
      }
      #pragma unroll
      for (int j = 0; j < 8; ++j) if (!any) keep[j] = true;

      const int r = tl >> 3, myrow = tl & 7;
      const int first = (r == 0) ? 1 : 0;
      double vre[8], vim[8];
      #pragma unroll
      for (int cc = 0; cc < 8; ++cc) {
        vre[cc] = Kd[myrow * 8 + cc] - ((myrow == cc) ? lre[first] : 0.0);
        vim[cc] = (myrow == cc) ? -lim[first] : 0.0;
      }
      #pragma unroll
      for (int j = 0; j < 8; ++j) {
        if (j == r || j == first) continue;
        double nre[8], nim[8];
        #pragma unroll
        for (int cc = 0; cc < 8; ++cc) {
          double are = 0.0, aim = 0.0;
          #pragma unroll
          for (int k = 0; k < 8; ++k) {
            double bre = Kd[k * 8 + cc] - ((k == cc) ? lre[j] : 0.0);
            double bim = (k == cc) ? -lim[j] : 0.0;
            are += vre[k] * bre - vim[k] * bim;
            aim += vre[k] * bim + vim[k] * bre;
          }
          nre[cc] = are; nim[cc] = aim;
        }
        #pragma unroll
        for (int cc = 0; cc < 8; ++cc) { vre[cc] = nre[cc]; vim[cc] = nim[cc]; }
      }

      double dre = 1.0, dim = 0.0;
      #pragma unroll
      for (int j = 0; j < 8; ++j) {
        if (j == r) continue;
        double ure = lre[r] - lre[j], uim = lim[r] - lim[j];
        double t1 = dre * ure - dim * uim;
        double t2 = dre * uim + dim * ure;
        dre = t1; dim = t2;
      }
      double numre = keep[r] ? (lre[r] + 1e-10) : 0.0;
      double numim = keep[r] ? (lim[r] + 1e-10) : 0.0;
      double dd = dre * dre + dim * dim;
      if (dd < 1e-300) dd = 1e-300;
      double cre = (numre * dre + numim * dim) / dd;
      double cim = (numim * dre - numre * dim) / dd;

      #pragma unroll
      for (int cc = 0; cc < 8; ++cc)
        Gpart[tl][cc] = cre * vre[cc] - cim * vim[cc];
    }
    __syncthreads();

    if (t < 64) {
      double sum = 0.0;
      #pragma unroll
      for (int rr = 0; rr < 8; ++rr) sum += Gpart[rr * 8 + (t >> 3)][t & 7];
      Gout[b * 64 + t] = (float)sum;
    }
    return;
  }

  if (b < 48) {
    int n = (b - 32) * 256 + t;
    if (n < 4096) {
      const float* rowp = comm + n * 32;
      float best = rowp[0];
      int bi = 0;
      #pragma unroll
      for (int c = 1; c < 32; ++c) {
        float v = rowp[c];
        if (v > best) { best = v; bi = c; }
      }
      cls[n] = bi;
    }
    return;
  }

  // wpack: 42 frags (single bf16 plane), K-slot-permuted
  {
    int gid = (b - 48) * 256 + t;
    if (gid >= 42 * 64) return;
    int fid = gid >> 6, lane = gid & 63;
    int i = fid / 14, fl = fid % 14;
    int c = lane & 15, g = lane >> 4;

    unsigned short vals[8];
    #pragma unroll
    for (int j = 0; j < 8; ++j) {
      float v = 0.f;
      if (fl < 4) {
        int nb = fl;
        int k = 8 * g + j;  // natural
        if (k < 12) v = W0[i * 768 + k * 64 + 16 * nb + c];
      } else if (fl < 12) {
        int q = fl - 4; int kb = q >> 2, nb = q & 3;
        int k = 32 * kb + 16 * ((j >> 2) & 1) + 4 * g + 2 * ((j >> 1) & 1) + (j & 1);
        v = W1[i * 4096 + k * 64 + 16 * nb + c];
      } else {
        int kb = fl - 12;
        int k = 32 * kb + 16 * ((j >> 2) & 1) + 4 * g + 2 * ((j >> 1) & 1) + (j & 1);
        if (c < 8) v = W2[i * 512 + k * 8 + c];
      }
      vals[j] = bf16_rn(v);
    }
    u32x4 o;
    #pragma unroll
    for (int tt = 0; tt < 4; ++tt)
      o[tt] = (unsigned)vals[2 * tt] | ((unsigned)vals[2 * tt + 1] << 16);
    *(u32x4*)(wfrag + fid * 256 + lane * 4) = o;
  }
}

// ---------------------------------------------------------------------------
// Main: R17 structure (best: 133.5us main) with intrinsic bf16 packing
// (compiler-scheduled v_cvt_pk_bf16_f32 instead of inline asm — m240).
// ---------------------------------------------------------------------------
#define SPB 256

__global__ __launch_bounds__(256, 2) void causal_mfma_kernel(
    const float* __restrict__ latent, const float* __restrict__ graphs,
    const int* __restrict__ cls, const unsigned* __restrict__ wfrag,
    const float* __restrict__ b0, const float* __restrict__ b1,
    const float* __restrict__ b2, float* __restrict__ out)
{
  __shared__ unsigned wsh[42 * 256];   // 43008 B: weight fragments
  __shared__ float    bsh[408];        // 1632 B
  __shared__ char     ex[4][2048];     // 8192 B: per-wave exchange (32B rows)

  const int t = threadIdx.x;
  const int lane = t & 63;
  const int w = t >> 6;
  const int c = lane & 15;
  const int g = lane >> 4;
  const int s = blockIdx.x * SPB + t;
  char* my = ex[w];

  // ---- stage weights + biases into LDS (once per block)
  #pragma unroll
  for (int q = 0; q < 11; ++q) {
    int idx = q * 256 + t;
    if (idx < 42 * 64)
      *(u32x4*)(wsh + idx * 4) = *(const u32x4*)(wfrag + idx * 4);
  }
  for (int idx = t; idx < 408; idx += 256) {
    bsh[idx] = (idx < 192) ? b0[idx] : (idx < 384) ? b1[idx - 192] : b2[idx - 384];
  }

  float x[8];
  {
    const float4 xa = *(const float4*)(latent + (size_t)s * 8);
    const float4 xb = *(const float4*)(latent + (size_t)s * 8 + 4);
    x[0] = xa.x; x[1] = xa.y; x[2] = xa.z; x[3] = xa.w;
    x[4] = xb.x; x[5] = xb.y; x[6] = xb.z; x[7] = xb.w;
  }
  unsigned parP0, parP1;
  u32x4 hi4;
  {
    float par[8];
    const int n = (s >> 4) & 4095;
    const float* G = graphs + cls[n] * 64;
    #pragma unroll
    for (int e = 0; e < 8; ++e) par[e] = 0.f;
    #pragma unroll
    for (int d = 0; d < 8; ++d) {
      const float xd = x[d];
      const float4 g0 = *(const float4*)(G + d * 8);
      const float4 g1 = *(const float4*)(G + d * 8 + 4);
      par[0] += xd * g0.x; par[1] += xd * g0.y; par[2] += xd * g0.z; par[3] += xd * g0.w;
      par[4] += xd * g1.x; par[5] += xd * g1.y; par[6] += xd * g1.z; par[7] += xd * g1.w;
    }
    parP0 = cvt_pk_bf16(par[0], par[1]);
    parP1 = cvt_pk_bf16(par[2], par[3]);
    hi4[0] = cvt_pk_bf16(par[4], par[5]);
    hi4[1] = cvt_pk_bf16(par[6], par[7]);
    hi4[2] = 0u; hi4[3] = 0u;
  }

  __syncthreads();  // staged LDS ready

  const char* wl = (const char*)wsh + lane * 16;
  char* a_u  = my + lane * 32;
  char* a_b0 = my + (c)      * 32 + g * 16;
  char* a_b1 = my + (16 + c) * 32 + g * 16;
  char* a_b2 = my + (32 + c) * 32 + g * 16;
  char* a_b3 = my + (48 + c) * 32 + g * 16;

  float logdet = 0.f;

  #pragma unroll
  for (int i = 0; i < 3; ++i) {
    const int in0 = (i & 1) ? 4 : 0;
    const int tr0 = (i & 1) ? 0 : 4;
    const char* wbase = wl + (size_t)(i * 14) * 1024;

    // ---- U write (slot0 = x-half+par[0..3]; slot1 = constant hi4)
    {
      u32x4 lo4;
      lo4[0] = cvt_pk_bf16(x[in0], x[in0 + 1]);
      lo4[1] = cvt_pk_bf16(x[in0 + 2], x[in0 + 3]);
      lo4[2] = parP0; lo4[3] = parP1;
      cbar();  // previous-iter O reads precede overwrite (in-order LDS)
      *(u32x4*)a_u = lo4;
      *(u32x4*)(a_u + 16) = hi4;
      cbar();  // U writes precede B1 reads
    }

    u32x4 B1[4];
    {
      u32x4 z = {0u, 0u, 0u, 0u};
      B1[0] = (g < 2) ? *(const u32x4*)a_b0 : z;
      B1[1] = (g < 2) ? *(const u32x4*)a_b1 : z;
      B1[2] = (g < 2) ? *(const u32x4*)a_b2 : z;
      B1[3] = (g < 2) ? *(const u32x4*)a_b3 : z;
      pin4u(B1[0]); pin4u(B1[1]); pin4u(B1[2]); pin4u(B1[3]);
    }

    // ---- Phase A: L1 nb=0,1 -> B2k0
    u32x4 B2k0[4], B2k1[4];
    {
      f32x4 a0[4], a1[4];
      bf16x8 A0 = *(const bf16x8*)(wbase + 0 * 1024);
      bf16x8 A1 = *(const bf16x8*)(wbase + 1 * 1024);
      f32x4 bv0 = *(const f32x4*)(bsh + i * 64 + 0 * 16 + g * 4);
      f32x4 bv1 = *(const f32x4*)(bsh + i * 64 + 1 * 16 + g * 4);
      #pragma unroll
      for (int mb = 0; mb < 4; ++mb) {
        a0[mb] = __builtin_amdgcn_mfma_f32_16x16x32_bf16(
            A0, __builtin_bit_cast(bf16x8, B1[mb]), bv0, 0, 0, 0);
        pin4f(a0[mb]);
      }
      #pragma unroll
      for (int mb = 0; mb < 4; ++mb) {
        a1[mb] = __builtin_amdgcn_mfma_f32_16x16x32_bf16(
            A1, __builtin_bit_cast(bf16x8, B1[mb]), bv1, 0, 0, 0);
        pin4f(a1[mb]);
      }
      #pragma unroll
      for (int mb = 0; mb < 4; ++mb) {
        B2k0[mb] = u32x4{cvt_pk_bf16(fmaxf(a0[mb][0], 0.f), fmaxf(a0[mb][1], 0.f)),
                         cvt_pk_bf16(fmaxf(a0[mb][2], 0.f), fmaxf(a0[mb][3], 0.f)),
                         cvt_pk_bf16(fmaxf(a1[mb][0], 0.f), fmaxf(a1[mb][1], 0.f)),
                         cvt_pk_bf16(fmaxf(a1[mb][2], 0.f), fmaxf(a1[mb][3], 0.f))};
        pin4u(B2k0[mb]);
      }
    }
    // ---- Phase B: L1 nb=2,3 -> B2k1
    {
      f32x4 a0[4], a1[4];
      bf16x8 A0 = *(const bf16x8*)(wbase + 2 * 1024);
      bf16x8 A1 = *(const bf16x8*)(wbase + 3 * 1024);
      f32x4 bv0 = *(const f32x4*)(bsh + i * 64 + 2 * 16 + g * 4);
      f32x4 bv1 = *(const f32x4*)(bsh + i * 64 + 3 * 16 + g * 4);
      #pragma unroll
      for (int mb = 0; mb < 4; ++mb) {
        a0[mb] = __builtin_amdgcn_mfma_f32_16x16x32_bf16(
            A0, __builtin_bit_cast(bf16x8, B1[mb]), bv0, 0, 0, 0);
        pin4f(a0[mb]);
      }
      #pragma unroll
      for (int mb = 0; mb < 4; ++mb) {
        a1[mb] = __builtin_amdgcn_mfma_f32_16x16x32_bf16(
            A1, __builtin_bit_cast(bf16x8, B1[mb]), bv1, 0, 0, 0);
        pin4f(a1[mb]);
      }
      #pragma unroll
      for (int mb = 0; mb < 4; ++mb) {
        B2k1[mb] = u32x4{cvt_pk_bf16(fmaxf(a0[mb][0], 0.f), fmaxf(a0[mb][1], 0.f)),
                         cvt_pk_bf16(fmaxf(a0[mb][2], 0.f), fmaxf(a0[mb][3], 0.f)),
                         cvt_pk_bf16(fmaxf(a1[mb][0], 0.f), fmaxf(a1[mb][1], 0.f)),
                         cvt_pk_bf16(fmaxf(a1[mb][2], 0.f), fmaxf(a1[mb][3], 0.f))};
        pin4u(B2k1[mb]);
      }
    }

    // ---- Phase C: L2 nb=0,1 -> B3k0
    u32x4 B3k0[4], B3k1[4];
    {
      f32x4 a0[4], a1[4];
      bf16x8 Ak0n0 = *(const bf16x8*)(wbase + (4 + 0) * 1024);
      bf16x8 Ak0n1 = *(const bf16x8*)(wbase + (4 + 1) * 1024);
      bf16x8 Ak1n0 = *(const bf16x8*)(wbase + (8 + 0) * 1024);
      bf16x8 Ak1n1 = *(const bf16x8*)(wbase + (8 + 1) * 1024);
      f32x4 bv0 = *(const f32x4*)(bsh + 192 + i * 64 + 0 * 16 + g * 4);
      f32x4 bv1 = *(const f32x4*)(bsh + 192 + i * 64 + 1 * 16 + g * 4);
      #pragma unroll
      for (int mb = 0; mb < 4; ++mb) {
        a0[mb] = __builtin_amdgcn_mfma_f32_16x16x32_bf16(
            Ak0n0, __builtin_bit_cast(bf16x8, B2k0[mb]), bv0, 0, 0, 0);
        a0[mb] = __builtin_amdgcn_mfma_f32_16x16x32_bf16(
            Ak1n0, __builtin_bit_cast(bf16x8, B2k1[mb]), a0[mb], 0, 0, 0);
        pin4f(a0[mb]);
      }
      #pragma unroll
      for (int mb = 0; mb < 4; ++mb) {
        a1[mb] = __builtin_amdgcn_mfma_f32_16x16x32_bf16(
            Ak0n1, __builtin_bit_cast(bf16x8, B2k0[mb]), bv1, 0, 0, 0);
        a1[mb] = __builtin_amdgcn_mfma_f32_16x16x32_bf16(
            Ak1n1, __builtin_bit_cast(bf16x8, B2k1[mb]), a1[mb], 0, 0, 0);
        pin4f(a1[mb]);
      }
      #pragma unroll
      for (int mb = 0; mb < 4; ++mb) {
        B3k0[mb] = u32x4{cvt_pk_bf16(fmaxf(a0[mb][0], 0.f), fmaxf(a0[mb][1], 0.f)),
                         cvt_pk_bf16(fmaxf(a0[mb][2], 0.f), fmaxf(a0[mb][3], 0.f)),
                         cvt_pk_bf16(fmaxf(a1[mb][0], 0.f), fmaxf(a1[mb][1], 0.f)),
                         cvt_pk_bf16(fmaxf(a1[mb][2], 0.f), fmaxf(a1[mb][3], 0.f))};
        pin4u(B3k0[mb]);
      }
    }
    // ---- Phase D: L2 nb=2,3 -> B3k1
    {
      f32x4 a0[4], a1[4];
      bf16x8 Ak0n2 = *(const bf16x8*)(wbase + (4 + 2) * 1024);
      bf16x8 Ak0n3 = *(const bf16x8*)(wbase + (4 + 3) * 1024);
      bf16x8 Ak1n2 = *(const bf16x8*)(wbase + (8 + 2) * 1024);
      bf16x8 Ak1n3 = *(const bf16x8*)(wbase + (8 + 3) * 1024);
      f32x4 bv0 = *(const f32x4*)(bsh + 192 + i * 64 + 2 * 16 + g * 4);
      f32x4 bv1 = *(const f32x4*)(bsh + 192 + i * 64 + 3 * 16 + g * 4);
      #pragma unroll
      for (int mb = 0; mb < 4; ++mb) {
        a0[mb] = __builtin_amdgcn_mfma_f32_16x16x32_bf16(
            Ak0n2, __builtin_bit_cast(bf16x8, B2k0[mb]), bv0, 0, 0, 0);
        a0[mb] = __builtin_amdgcn_mfma_f32_16x16x32_bf16(
            Ak1n2, __builtin_bit_cast(bf16x8, B2k1[mb]), a0[mb], 0, 0, 0);
        pin4f(a0[mb]);
      }
      #pragma unroll
      for (int mb = 0; mb < 4; ++mb) {
        a1[mb] = __builtin_amdgcn_mfma_f32_16x16x32_bf16(
            Ak0n3, __builtin_bit_cast(bf16x8, B2k0[mb]), bv1, 0, 0, 0);
        a1[mb] = __builtin_amdgcn_mfma_f32_16x16x32_bf16(
            Ak1n3, __builtin_bit_cast(bf16x8, B2k1[mb]), a1[mb], 0, 0, 0);
        pin4f(a1[mb]);
      }
      #pragma unroll
      for (int mb = 0; mb < 4; ++mb) {
        B3k1[mb] = u32x4{cvt_pk_bf16(fmaxf(a0[mb][0], 0.f), fmaxf(a0[mb][1], 0.f)),
                         cvt_pk_bf16(fmaxf(a0[mb][2], 0.f), fmaxf(a0[mb][3], 0.f)),
                         cvt_pk_bf16(fmaxf(a1[mb][0], 0.f), fmaxf(a1[mb][1], 0.f)),
                         cvt_pk_bf16(fmaxf(a1[mb][2], 0.f), fmaxf(a1[mb][3], 0.f))};
        pin4u(B3k1[mb]);
      }
    }

    // ---- Phase E: L3 chained
    f32x4 acc3[4];
    {
      bf16x8 A0 = *(const bf16x8*)(wbase + 12 * 1024);
      bf16x8 A1 = *(const bf16x8*)(wbase + 13 * 1024);
      f32x4 z = {0.f, 0.f, 0.f, 0.f};
      f32x4 bC2 = (g < 2) ? *(const f32x4*)(bsh + 384 + i * 8 + g * 4) : z;
      #pragma unroll
      for (int mb = 0; mb < 4; ++mb) {
        f32x4 tmp = __builtin_amdgcn_mfma_f32_16x16x32_bf16(
            A0, __builtin_bit_cast(bf16x8, B3k0[mb]), bC2, 0, 0, 0);
        acc3[mb] = __builtin_amdgcn_mfma_f32_16x16x32_bf16(
            A1, __builtin_bit_cast(bf16x8, B3k1[mb]), tmp, 0, 0, 0);
        pin4f(acc3[mb]);
      }
    }

    // ---- O write (g<2 rows hold the 8 real output features)
    cbar();  // B1 reads precede O overwrite (in-order LDS)
    if (g < 2) {
      *(u32x4*)a_b0 = __builtin_bit_cast(u32x4, acc3[0]);
      *(u32x4*)a_b1 = __builtin_bit_cast(u32x4, acc3[1]);
      *(u32x4*)a_b2 = __builtin_bit_cast(u32x4, acc3[2]);
      *(u32x4*)a_b3 = __builtin_bit_cast(u32x4, acc3[3]);
    }
    cbar();  // O writes precede epilogue reads

    // ---- epilogue
    {
      u32x4 o0 = *(const u32x4*)a_u;
      u32x4 o1 = *(const u32x4*)(a_u + 16);
      float sv0 = tanh_fast(__uint_as_float(o0[0]));
      float sv1 = tanh_fast(__uint_as_float(o0[1]));
      float sv2 = tanh_fast(__uint_as_float(o0[2]));
      float sv3 = tanh_fast(__uint_as_float(o0[3]));
      x[tr0 + 0] = x[tr0 + 0] * __expf(sv0) + __uint_as_float(o1[0]);
      x[tr0 + 1] = x[tr0 + 1] * __expf(sv1) + __uint_as_float(o1[1]);
      x[tr0 + 2] = x[tr0 + 2] * __expf(sv2) + __uint_as_float(o1[2]);
      x[tr0 + 3] = x[tr0 + 3] * __expf(sv3) + __uint_as_float(o1[3]);
      logdet += sv0 + sv1 + sv2 + sv3;
    }
  }

  float ss = 0.f;
  #pragma unroll
  for (int q = 0; q < 8; ++q) ss += x[q] * x[q];
  out[s] = -0.5f * ss - 7.3515082656373810f + logdet;
}

// ---------------------------------------------------------------------------
extern "C" void kernel_launch(void* const* d_in, const int* in_sizes, int n_in,
                              void* d_out, int out_size, void* d_ws, size_t ws_size,
                              hipStream_t stream) {
  const float* latent  = (const float*)d_in[0];
  const float* koopman = (const float*)d_in[1];
  const float* comm    = (const float*)d_in[2];
  const float* W0      = (const float*)d_in[3];
  const float* b0      = (const float*)d_in[4];
  const float* W1      = (const float*)d_in[5];
  const float* b1      = (const float*)d_in[6];
  const float* W2      = (const float*)d_in[7];
  const float* b2      = (const float*)d_in[8];
  float* out = (float*)d_out;

  float*    graphs_ws = (float*)d_ws;                        // 8 KB
  int*      cls_ws    = (int*)((char*)d_ws + 8192);          // 16 KB
  unsigned* wfrag_ws  = (unsigned*)((char*)d_ws + 24576);    // 42 KB

  // blocks: 0..31 eig | 32..47 argmax | 48..58 wpack
  prologue_kernel<<<59, 256, 0, stream>>>(
      koopman, comm, W0, W1, W2, graphs_ws, cls_ws, wfrag_ws);

  const int total = 32 * 4096 * 16;  // 2,097,152 samples
  causal_mfma_kernel<<<total / SPB, SPB, 0, stream>>>(
      latent, graphs_ws, cls_ws, wfrag_ws, b0, b1, b2, out);
}

// Round 20
// 137.014 us; speedup vs baseline: 1.2205x; 1.2205x over previous
//
#include <hip/hip_runtime.h>
#include <hip/hip_bf16.h>

typedef __attribute__((ext_vector_type(8))) short     bf16x8;
typedef __attribute__((ext_vector_type(4))) float     f32x4;
typedef __attribute__((ext_vector_type(4))) unsigned  u32x4;

// ---------------------------------------------------------------------------
// helpers
// ---------------------------------------------------------------------------
__device__ inline unsigned short bf16_rn(float x) {
  unsigned u = __float_as_uint(x);
  unsigned r = (u + 0x7FFFu + ((u >> 16) & 1u)) >> 16;
  return (unsigned short)r;
}
// inline-asm packed bf16 convert — R19 proved the intrinsic path is ~2-4
// VALU ops/convert (main +24%); this single-instruction form is the fastest.
__device__ inline unsigned cvt_pk_bf16(float a, float b) {
  unsigned r;
  asm("v_cvt_pk_bf16_f32 %0, %1, %2" : "=v"(r) : "v"(a), "v"(b));
  return r;  // low16 = bf16(a), high16 = bf16(b)
}
__device__ inline void pin4f(f32x4& v) { asm("" : "+v"(v)); }
__device__ inline void pin4u(u32x4& v) { asm("" : "+v"(v)); }
// compile-time-only ordering pin (per-wave LDS is in-order in HW; R7/R17)
__device__ inline void cbar() { asm volatile("" ::: "memory"); }
__device__ inline float tanh_fast(float v) {
  float vv = fminf(fmaxf(v, -15.f), 15.f);
  float e = __expf(2.f * vv);
  return (e - 1.f) * __builtin_amdgcn_rcpf(e + 1.f);
}

// ---------------------------------------------------------------------------
// Merged prologue: blocks 0..31 eig | 32..47 argmax | 48..58 wpack
// DK iters = 20 (validated: R19 passed with absmax 4.0 at 20 iters).
// ---------------------------------------------------------------------------
__global__ __launch_bounds__(256) void prologue_kernel(
    const float* __restrict__ Kt, const float* __restrict__ comm,
    const float* __restrict__ W0, const float* __restrict__ W1,
    const float* __restrict__ W2,
    float* __restrict__ Gout, int* __restrict__ cls,
    unsigned* __restrict__ wfrag)
{
  const int b = blockIdx.x;
  const int t = threadIdx.x;

  if (b < 32) {
    __shared__ double Kd[64];
    __shared__ double Pw[2][64];
    __shared__ double psum[8];
    __shared__ double coefs[9];
    __shared__ double rts[16];
    __shared__ double Gpart[64][8];

    const int tl = t & 63;
    const int row = tl >> 3, col = tl & 7;

    if (t < 64) Kd[tl] = (double)Kt[b * 64 + tl];
    __syncthreads();
    if (t < 64) Pw[0][tl] = Kd[tl];
    __syncthreads();

    int cur = 0;
    for (int p = 1; p <= 8; ++p) {
      if (t == 0) {
        double tr = 0.0;
        for (int d = 0; d < 8; ++d) tr += Pw[cur][d * 9];
        psum[p - 1] = tr;
      }
      if (p < 8 && t < 64) {
        double sacc = 0.0;
        for (int k = 0; k < 8; ++k) sacc += Pw[cur][row * 8 + k] * Kd[k * 8 + col];
        Pw[cur ^ 1][tl] = sacc;
      }
      __syncthreads();
      cur ^= 1;
    }

    if (t == 0) {
      double a[9];
      a[0] = 1.0;
      for (int k = 1; k <= 8; ++k) {
        double ssum = psum[k - 1];
        for (int i = 1; i < k; ++i) ssum += a[i] * psum[k - i - 1];
        a[k] = -ssum / (double)k;
      }
      for (int k = 0; k <= 8; ++k) coefs[k] = a[k];
    }
    __syncthreads();

    if (t < 8) {
      double a8[9];
      #pragma unroll
      for (int k = 0; k <= 8; ++k) a8[k] = coefs[k];
      double zre = 1.0, zim = 0.0;
      for (int q = 0; q <= t; ++q) {
        double t1 = zre * 0.4 - zim * 0.9;
        double t2 = zre * 0.9 + zim * 0.4;
        zre = t1; zim = t2;
      }
      for (int it = 0; it < 20; ++it) {
        double pre = a8[0], pim = 0.0;
        #pragma unroll
        for (int k = 1; k <= 8; ++k) {
          double t1 = pre * zre - pim * zim + a8[k];
          double t2 = pre * zim + pim * zre;
          pre = t1; pim = t2;
        }
        double dre = 1.0, dim = 0.0;
        for (int j = 0; j < 8; ++j) {
          double ore = __shfl(zre, j, 64);
          double oim = __shfl(zim, j, 64);
          if (j != t) {
            double sre = zre - ore, sim = zim - oim;
            double t1 = dre * sre - dim * sim;
            double t2 = dre * sim + dim * sre;
            dre = t1; dim = t2;
          }
        }
        double d2 = dre * dre + dim * dim;
        if (d2 < 1e-60) d2 = 1e-60;
        double qre = (pre * dre + pim * dim) / d2;
        double qim = (pim * dre - pre * dim) / d2;
        zre -= qre; zim -= qim;
      }
      rts[t] = zre; rts[8 + t] = zim;
    }
    __syncthreads();

    if (t < 64) {
      double lre[8], lim[8];
      #pragma unroll
      for (int j = 0; j < 8; ++j) { lre[j] = rts[j]; lim[j] = rts[8 + j]; }

      bool keep[8]; bool any = false;
      #pragma unroll
      for (int j = 0; j < 8; ++j) {
        double sre = lre[j] + 1e-10, sim = lim[j] + 1e-10;
        double amod = sqrt(sre * sre + sim * sim);
        keep[j] = (amod <= 1.1) && (amod >= 0.9);
        any = any || keep[j];
      }
      #pragma unroll
      for (int j = 0; j < 8; ++j) if (!any) keep[j] = true;

      const int r = tl >> 3, myrow = tl & 7;
      const int first = (r == 0) ? 1 : 0;
      double vre[8], vim[8];
      #pragma unroll
      for (int cc = 0; cc < 8; ++cc) {
        vre[cc] = Kd[myrow * 8 + cc] - ((myrow == cc) ? lre[first] : 0.0);
        vim[cc] = (myrow == cc) ? -lim[first] : 0.0;
      }
      #pragma unroll
      for (int j = 0; j < 8; ++j) {
        if (j == r || j == first) continue;
        double nre[8], nim[8];
        #pragma unroll
        for (int cc = 0; cc < 8; ++cc) {
          double are = 0.0, aim = 0.0;
          #pragma unroll
          for (int k = 0; k < 8; ++k) {
            double bre = Kd[k * 8 + cc] - ((k == cc) ? lre[j] : 0.0);
            double bim = (k == cc) ? -lim[j] : 0.0;
            are += vre[k] * bre - vim[k] * bim;
            aim += vre[k] * bim + vim[k] * bre;
          }
          nre[cc] = are; nim[cc] = aim;
        }
        #pragma unroll
        for (int cc = 0; cc < 8; ++cc) { vre[cc] = nre[cc]; vim[cc] = nim[cc]; }
      }

      double dre = 1.0, dim = 0.0;
      #pragma unroll
      for (int j = 0; j < 8; ++j) {
        if (j == r) continue;
        double ure = lre[r] - lre[j], uim = lim[r] - lim[j];
        double t1 = dre * ure - dim * uim;
        double t2 = dre * uim + dim * ure;
        dre = t1; dim = t2;
      }
      double numre = keep[r] ? (lre[r] + 1e-10) : 0.0;
      double numim = keep[r] ? (lim[r] + 1e-10) : 0.0;
      double dd = dre * dre + dim * dim;
      if (dd < 1e-300) dd = 1e-300;
      double cre = (numre * dre + numim * dim) / dd;
      double cim = (numim * dre - numre * dim) / dd;

      #pragma unroll
      for (int cc = 0; cc < 8; ++cc)
        Gpart[tl][cc] = cre * vre[cc] - cim * vim[cc];
    }
    __syncthreads();

    if (t < 64) {
      double sum = 0.0;
      #pragma unroll
      for (int rr = 0; rr < 8; ++rr) sum += Gpart[rr * 8 + (t >> 3)][t & 7];
      Gout[b * 64 + t] = (float)sum;
    }
    return;
  }

  if (b < 48) {
    int n = (b - 32) * 256 + t;
    if (n < 4096) {
      const float* rowp = comm + n * 32;
      float best = rowp[0];
      int bi = 0;
      #pragma unroll
      for (int c = 1; c < 32; ++c) {
        float v = rowp[c];
        if (v > best) { best = v; bi = c; }
      }
      cls[n] = bi;
    }
    return;
  }

  // wpack: 42 frags (single bf16 plane), K-slot-permuted
  {
    int gid = (b - 48) * 256 + t;
    if (gid >= 42 * 64) return;
    int fid = gid >> 6, lane = gid & 63;
    int i = fid / 14, fl = fid % 14;
    int c = lane & 15, g = lane >> 4;

    unsigned short vals[8];
    #pragma unroll
    for (int j = 0; j < 8; ++j) {
      float v = 0.f;
      if (fl < 4) {
        int nb = fl;
        int k = 8 * g + j;  // natural
        if (k < 12) v = W0[i * 768 + k * 64 + 16 * nb + c];
      } else if (fl < 12) {
        int q = fl - 4; int kb = q >> 2, nb = q & 3;
        int k = 32 * kb + 16 * ((j >> 2) & 1) + 4 * g + 2 * ((j >> 1) & 1) + (j & 1);
        v = W1[i * 4096 + k * 64 + 16 * nb + c];
      } else {
        int kb = fl - 12;
        int k = 32 * kb + 16 * ((j >> 2) & 1) + 4 * g + 2 * ((j >> 1) & 1) + (j & 1);
        if (c < 8) v = W2[i * 512 + k * 8 + c];
      }
      vals[j] = bf16_rn(v);
    }
    u32x4 o;
    #pragma unroll
    for (int tt = 0; tt < 4; ++tt)
      o[tt] = (unsigned)vals[2 * tt] | ((unsigned)vals[2 * tt + 1] << 16);
    *(u32x4*)(wfrag + fid * 256 + lane * 4) = o;
  }
}

// ---------------------------------------------------------------------------
// Main: R17 verbatim (best passing main: 133.5us) — inline-asm cvt_pk,
// cbar ordering, VGPR pins, LDS-staged weights/biases.
// ---------------------------------------------------------------------------
#define SPB 256

__global__ __launch_bounds__(256, 2) void causal_mfma_kernel(
    const float* __restrict__ latent, const float* __restrict__ graphs,
    const int* __restrict__ cls, const unsigned* __restrict__ wfrag,
    const float* __restrict__ b0, const float* __restrict__ b1,
    const float* __restrict__ b2, float* __restrict__ out)
{
  __shared__ unsigned wsh[42 * 256];   // 43008 B: weight fragments
  __shared__ float    bsh[408];        // 1632 B
  __shared__ char     ex[4][2048];     // 8192 B: per-wave exchange (32B rows)

  const int t = threadIdx.x;
  const int lane = t & 63;
  const int w = t >> 6;
  const int c = lane & 15;
  const int g = lane >> 4;
  const int s = blockIdx.x * SPB + t;
  char* my = ex[w];

  // ---- stage weights + biases into LDS (once per block)
  #pragma unroll
  for (int q = 0; q < 11; ++q) {
    int idx = q * 256 + t;
    if (idx < 42 * 64)
      *(u32x4*)(wsh + idx * 4) = *(const u32x4*)(wfrag + idx * 4);
  }
  for (int idx = t; idx < 408; idx += 256) {
    bsh[idx] = (idx < 192) ? b0[idx] : (idx < 384) ? b1[idx - 192] : b2[idx - 384];
  }

  float x[8];
  {
    const float4 xa = *(const float4*)(latent + (size_t)s * 8);
    const float4 xb = *(const float4*)(latent + (size_t)s * 8 + 4);
    x[0] = xa.x; x[1] = xa.y; x[2] = xa.z; x[3] = xa.w;
    x[4] = xb.x; x[5] = xb.y; x[6] = xb.z; x[7] = xb.w;
  }
  unsigned parP0, parP1;
  u32x4 hi4;
  {
    float par[8];
    const int n = (s >> 4) & 4095;
    const float* G = graphs + cls[n] * 64;
    #pragma unroll
    for (int e = 0; e < 8; ++e) par[e] = 0.f;
    #pragma unroll
    for (int d = 0; d < 8; ++d) {
      const float xd = x[d];
      const float4 g0 = *(const float4*)(G + d * 8);
      const float4 g1 = *(const float4*)(G + d * 8 + 4);
      par[0] += xd * g0.x; par[1] += xd * g0.y; par[2] += xd * g0.z; par[3] += xd * g0.w;
      par[4] += xd * g1.x; par[5] += xd * g1.y; par[6] += xd * g1.z; par[7] += xd * g1.w;
    }
    parP0 = cvt_pk_bf16(par[0], par[1]);
    parP1 = cvt_pk_bf16(par[2], par[3]);
    hi4[0] = cvt_pk_bf16(par[4], par[5]);
    hi4[1] = cvt_pk_bf16(par[6], par[7]);
    hi4[2] = 0u; hi4[3] = 0u;
  }

  __syncthreads();  // staged LDS ready

  const char* wl = (const char*)wsh + lane * 16;
  char* a_u  = my + lane * 32;
  char* a_b0 = my + (c)      * 32 + g * 16;
  char* a_b1 = my + (16 + c) * 32 + g * 16;
  char* a_b2 = my + (32 + c) * 32 + g * 16;
  char* a_b3 = my + (48 + c) * 32 + g * 16;

  float logdet = 0.f;

  #pragma unroll
  for (int i = 0; i < 3; ++i) {
    const int in0 = (i & 1) ? 4 : 0;
    const int tr0 = (i & 1) ? 0 : 4;
    const char* wbase = wl + (size_t)(i * 14) * 1024;

    // ---- U write (slot0 = x-half+par[0..3]; slot1 = constant hi4)
    {
      u32x4 lo4;
      lo4[0] = cvt_pk_bf16(x[in0], x[in0 + 1]);
      lo4[1] = cvt_pk_bf16(x[in0 + 2], x[in0 + 3]);
      lo4[2] = parP0; lo4[3] = parP1;
      cbar();  // previous-iter O reads precede overwrite (in-order LDS)
      *(u32x4*)a_u = lo4;
      *(u32x4*)(a_u + 16) = hi4;
      cbar();  // U writes precede B1 reads
    }

    u32x4 B1[4];
    {
      u32x4 z = {0u, 0u, 0u, 0u};
      B1[0] = (g < 2) ? *(const u32x4*)a_b0 : z;
      B1[1] = (g < 2) ? *(const u32x4*)a_b1 : z;
      B1[2] = (g < 2) ? *(const u32x4*)a_b2 : z;
      B1[3] = (g < 2) ? *(const u32x4*)a_b3 : z;
      pin4u(B1[0]); pin4u(B1[1]); pin4u(B1[2]); pin4u(B1[3]);
    }

    // ---- Phase A: L1 nb=0,1 -> B2k0
    u32x4 B2k0[4], B2k1[4];
    {
      f32x4 a0[4], a1[4];
      bf16x8 A0 = *(const bf16x8*)(wbase + 0 * 1024);
      bf16x8 A1 = *(const bf16x8*)(wbase + 1 * 1024);
      f32x4 bv0 = *(const f32x4*)(bsh + i * 64 + 0 * 16 + g * 4);
      f32x4 bv1 = *(const f32x4*)(bsh + i * 64 + 1 * 16 + g * 4);
      #pragma unroll
      for (int mb = 0; mb < 4; ++mb) {
        a0[mb] = __builtin_amdgcn_mfma_f32_16x16x32_bf16(
            A0, __builtin_bit_cast(bf16x8, B1[mb]), bv0, 0, 0, 0);
        pin4f(a0[mb]);
      }
      #pragma unroll
      for (int mb = 0; mb < 4; ++mb) {
        a1[mb] = __builtin_amdgcn_mfma_f32_16x16x32_bf16(
            A1, __builtin_bit_cast(bf16x8, B1[mb]), bv1, 0, 0, 0);
        pin4f(a1[mb]);
      }
      #pragma unroll
      for (int mb = 0; mb < 4; ++mb) {
        B2k0[mb] = u32x4{cvt_pk_bf16(fmaxf(a0[mb][0], 0.f), fmaxf(a0[mb][1], 0.f)),
                         cvt_pk_bf16(fmaxf(a0[mb][2], 0.f), fmaxf(a0[mb][3], 0.f)),
                         cvt_pk_bf16(fmaxf(a1[mb][0], 0.f), fmaxf(a1[mb][1], 0.f)),
                         cvt_pk_bf16(fmaxf(a1[mb][2], 0.f), fmaxf(a1[mb][3], 0.f))};
        pin4u(B2k0[mb]);
      }
    }
    // ---- Phase B: L1 nb=2,3 -> B2k1
    {
      f32x4 a0[4], a1[4];
      bf16x8 A0 = *(const bf16x8*)(wbase + 2 * 1024);
      bf16x8 A1 = *(const bf16x8*)(wbase + 3 * 1024);
      f32x4 bv0 = *(const f32x4*)(bsh + i * 64 + 2 * 16 + g * 4);
      f32x4 bv1 = *(const f32x4*)(bsh + i * 64 + 3 * 16 + g * 4);
      #pragma unroll
      for (int mb = 0; mb < 4; ++mb) {
        a0[mb] = __builtin_amdgcn_mfma_f32_16x16x32_bf16(
            A0, __builtin_bit_cast(bf16x8, B1[mb]), bv0, 0, 0, 0);
        pin4f(a0[mb]);
      }
      #pragma unroll
      for (int mb = 0; mb < 4; ++mb) {
        a1[mb] = __builtin_amdgcn_mfma_f32_16x16x32_bf16(
            A1, __builtin_bit_cast(bf16x8, B1[mb]), bv1, 0, 0, 0);
        pin4f(a1[mb]);
      }
      #pragma unroll
      for (int mb = 0; mb < 4; ++mb) {
        B2k1[mb] = u32x4{cvt_pk_bf16(fmaxf(a0[mb][0], 0.f), fmaxf(a0[mb][1], 0.f)),
                         cvt_pk_bf16(fmaxf(a0[mb][2], 0.f), fmaxf(a0[mb][3], 0.f)),
                         cvt_pk_bf16(fmaxf(a1[mb][0], 0.f), fmaxf(a1[mb][1], 0.f)),
                         cvt_pk_bf16(fmaxf(a1[mb][2], 0.f), fmaxf(a1[mb][3], 0.f))};
        pin4u(B2k1[mb]);
      }
    }

    // ---- Phase C: L2 nb=0,1 -> B3k0
    u32x4 B3k0[4], B3k1[4];
    {
      f32x4 a0[4], a1[4];
      bf16x8 Ak0n0 = *(const bf16x8*)(wbase + (4 + 0) * 1024);
      bf16x8 Ak0n1 = *(const bf16x8*)(wbase + (4 + 1) * 1024);
      bf16x8 Ak1n0 = *(const bf16x8*)(wbase + (8 + 0) * 1024);
      bf16x8 Ak1n1 = *(const bf16x8*)(wbase + (8 + 1) * 1024);
      f32x4 bv0 = *(const f32x4*)(bsh + 192 + i * 64 + 0 * 16 + g * 4);
      f32x4 bv1 = *(const f32x4*)(bsh + 192 + i * 64 + 1 * 16 + g * 4);
      #pragma unroll
      for (int mb = 0; mb < 4; ++mb) {
        a0[mb] = __builtin_amdgcn_mfma_f32_16x16x32_bf16(
            Ak0n0, __builtin_bit_cast(bf16x8, B2k0[mb]), bv0, 0, 0, 0);
        a0[mb] = __builtin_amdgcn_mfma_f32_16x16x32_bf16(
            Ak1n0, __builtin_bit_cast(bf16x8, B2k1[mb]), a0[mb], 0, 0, 0);
        pin4f(a0[mb]);
      }
      #pragma unroll
      for (int mb = 0; mb < 4; ++mb) {
        a1[mb] = __builtin_amdgcn_mfma_f32_16x16x32_bf16(
            Ak0n1, __builtin_bit_cast(bf16x8, B2k0[mb]), bv1, 0, 0, 0);
        a1[mb] = __builtin_amdgcn_mfma_f32_16x16x32_bf16(
            Ak1n1, __builtin_bit_cast(bf16x8, B2k1[mb]), a1[mb], 0, 0, 0);
        pin4f(a1[mb]);
      }
      #pragma unroll
      for (int mb = 0; mb < 4; ++mb) {
        B3k0[mb] = u32x4{cvt_pk_bf16(fmaxf(a0[mb][0], 0.f), fmaxf(a0[mb][1], 0.f)),
                         cvt_pk_bf16(fmaxf(a0[mb][2], 0.f), fmaxf(a0[mb][3], 0.f)),
                         cvt_pk_bf16(fmaxf(a1[mb][0], 0.f), fmaxf(a1[mb][1], 0.f)),
                         cvt_pk_bf16(fmaxf(a1[mb][2], 0.f), fmaxf(a1[mb][3], 0.f))};
        pin4u(B3k0[mb]);
      }
    }
    // ---- Phase D: L2 nb=2,3 -> B3k1
    {
      f32x4 a0[4], a1[4];
      bf16x8 Ak0n2 = *(const bf16x8*)(wbase + (4 + 2) * 1024);
      bf16x8 Ak0n3 = *(const bf16x8*)(wbase + (4 + 3) * 1024);
      bf16x8 Ak1n2 = *(const bf16x8*)(wbase + (8 + 2) * 1024);
      bf16x8 Ak1n3 = *(const bf16x8*)(wbase + (8 + 3) * 1024);
      f32x4 bv0 = *(const f32x4*)(bsh + 192 + i * 64 + 2 * 16 + g * 4);
      f32x4 bv1 = *(const f32x4*)(bsh + 192 + i * 64 + 3 * 16 + g * 4);
      #pragma unroll
      for (int mb = 0; mb < 4; ++mb) {
        a0[mb] = __builtin_amdgcn_mfma_f32_16x16x32_bf16(
            Ak0n2, __builtin_bit_cast(bf16x8, B2k0[mb]), bv0, 0, 0, 0);
        a0[mb] = __builtin_amdgcn_mfma_f32_16x16x32_bf16(
            Ak1n2, __builtin_bit_cast(bf16x8, B2k1[mb]), a0[mb], 0, 0, 0);
        pin4f(a0[mb]);
      }
      #pragma unroll
      for (int mb = 0; mb < 4; ++mb) {
        a1[mb] = __builtin_amdgcn_mfma_f32_16x16x32_bf16(
            Ak0n3, __builtin_bit_cast(bf16x8, B2k0[mb]), bv1, 0, 0, 0);
        a1[mb] = __builtin_amdgcn_mfma_f32_16x16x32_bf16(
            Ak1n3, __builtin_bit_cast(bf16x8, B2k1[mb]), a1[mb], 0, 0, 0);
        pin4f(a1[mb]);
      }
      #pragma unroll
      for (int mb = 0; mb < 4; ++mb) {
        B3k1[mb] = u32x4{cvt_pk_bf16(fmaxf(a0[mb][0], 0.f), fmaxf(a0[mb][1], 0.f)),
                         cvt_pk_bf16(fmaxf(a0[mb][2], 0.f), fmaxf(a0[mb][3], 0.f)),
                         cvt_pk_bf16(fmaxf(a1[mb][0], 0.f), fmaxf(a1[mb][1], 0.f)),
                         cvt_pk_bf16(fmaxf(a1[mb][2], 0.f), fmaxf(a1[mb][3], 0.f))};
        pin4u(B3k1[mb]);
      }
    }

    // ---- Phase E: L3 chained
    f32x4 acc3[4];
    {
      bf16x8 A0 = *(const bf16x8*)(wbase + 12 * 1024);
      bf16x8 A1 = *(const bf16x8*)(wbase + 13 * 1024);
      f32x4 z = {0.f, 0.f, 0.f, 0.f};
      f32x4 bC2 = (g < 2) ? *(const f32x4*)(bsh + 384 + i * 8 + g * 4) : z;
      #pragma unroll
      for (int mb = 0; mb < 4; ++mb) {
        f32x4 tmp = __builtin_amdgcn_mfma_f32_16x16x32_bf16(
            A0, __builtin_bit_cast(bf16x8, B3k0[mb]), bC2, 0, 0, 0);
        acc3[mb] = __builtin_amdgcn_mfma_f32_16x16x32_bf16(
            A1, __builtin_bit_cast(bf16x8, B3k1[mb]), tmp, 0, 0, 0);
        pin4f(acc3[mb]);
      }
    }

    // ---- O write (g<2 rows hold the 8 real output features)
    cbar();  // B1 reads precede O overwrite (in-order LDS)
    if (g < 2) {
      *(u32x4*)a_b0 = __builtin_bit_cast(u32x4, acc3[0]);
      *(u32x4*)a_b1 = __builtin_bit_cast(u32x4, acc3[1]);
      *(u32x4*)a_b2 = __builtin_bit_cast(u32x4, acc3[2]);
      *(u32x4*)a_b3 = __builtin_bit_cast(u32x4, acc3[3]);
    }
    cbar();  // O writes precede epilogue reads

    // ---- epilogue
    {
      u32x4 o0 = *(const u32x4*)a_u;
      u32x4 o1 = *(const u32x4*)(a_u + 16);
      float sv0 = tanh_fast(__uint_as_float(o0[0]));
      float sv1 = tanh_fast(__uint_as_float(o0[1]));
      float sv2 = tanh_fast(__uint_as_float(o0[2]));
      float sv3 = tanh_fast(__uint_as_float(o0[3]));
      x[tr0 + 0] = x[tr0 + 0] * __expf(sv0) + __uint_as_float(o1[0]);
      x[tr0 + 1] = x[tr0 + 1] * __expf(sv1) + __uint_as_float(o1[1]);
      x[tr0 + 2] = x[tr0 + 2] * __expf(sv2) + __uint_as_float(o1[2]);
      x[tr0 + 3] = x[tr0 + 3] * __expf(sv3) + __uint_as_float(o1[3]);
      logdet += sv0 + sv1 + sv2 + sv3;
    }
  }

  float ss = 0.f;
  #pragma unroll
  for (int q = 0; q < 8; ++q) ss += x[q] * x[q];
  out[s] = -0.5f * ss - 7.3515082656373810f + logdet;
}

// ---------------------------------------------------------------------------
extern "C" void kernel_launch(void* const* d_in, const int* in_sizes, int n_in,
                              void* d_out, int out_size, void* d_ws, size_t ws_size,
                              hipStream_t stream) {
  const float* latent  = (const float*)d_in[0];
  const float* koopman = (const float*)d_in[1];
  const float* comm    = (const float*)d_in[2];
  const float* W0      = (const float*)d_in[3];
  const float* b0      = (const float*)d_in[4];
  const float* W1      = (const float*)d_in[5];
  const float* b1      = (const float*)d_in[6];
  const float* W2      = (const float*)d_in[7];
  const float* b2      = (const float*)d_in[8];
  float* out = (float*)d_out;

  float*    graphs_ws = (float*)d_ws;                        // 8 KB
  int*      cls_ws    = (int*)((char*)d_ws + 8192);          // 16 KB
  unsigned* wfrag_ws  = (unsigned*)((char*)d_ws + 24576);    // 42 KB

  // blocks: 0..31 eig | 32..47 argmax | 48..58 wpack
  prologue_kernel<<<59, 256, 0, stream>>>(
      koopman, comm, W0, W1, W2, graphs_ws, cls_ws, wfrag_ws);

  const int total = 32 * 4096 * 16;  // 2,097,152 samples
  causal_mfma_kernel<<<total / SPB, SPB, 0, stream>>>(
      latent, graphs_ws, cls_ws, wfrag_ws, b0, b1, b2, out);
}